// Round 5
// baseline (361.158 us; speedup 1.0000x reference)
//
#include <hip/hip_runtime.h>

// ESSAttn bf16-MFMA version. b=8, C=64, H=W=256 (N=65536), fp32 in/out.
// Math (exact refactor of reference):
//   out[b,n,d] = x_col(n)@wvln[d,:] + bias2[d] + w_row[n] * sum_c q2[n,c]*kvw[b][c][d]
//   kvw[c][d]  = inv_k[c] * sum_e kvu[c][e]*w_ln[d][e],  inv_k = 1/(256*max(sqrt(ksq_c),1e-12))
//   kvu[c][e]  = sum_n k2t[n,c]*v[n,e],  ksq_c = sum_n k2t^2
//   k2t = (k-mean_c(k))^2/(k2s+1e-7),  q2 = (q-mean)^2, w_row folds q2 normalizations.
// Round 5 = round 4 resubmitted (container flake, no counters; kernel audited clean):
// k1 kvu fully in-register (accA layout == 16x16x16 MFMA operand layout), no kt/vt LDS,
// 1 barrier/tile; DPP row reductions; bf16 double-buffered x staging. k3 same staging/DPP,
// 2nd barrier dropped. k0/k2 unchanged.

typedef unsigned short u16;
typedef unsigned int u32;
typedef short bf16x8_t __attribute__((ext_vector_type(8)));
typedef short bf16x4_t __attribute__((ext_vector_type(4)));
typedef float f32x4_t __attribute__((ext_vector_type(4)));

#define NN 65536
#define G1 96
#define G3 192   // k3 persistent blocks per batch
#define STK 68   // bf16 qt LDS stride (elements)
#define SXB 68   // bf16 x-tile LDS stride (mult of 4 -> b64-aligned packed writes)

static __device__ __forceinline__ u16 f2bf(float f) {
    union { float f; u32 u; } v; v.f = f;
    u32 r = v.u + 0x7FFFu + ((v.u >> 16) & 1u);
    return (u16)(r >> 16);
}
static __device__ __forceinline__ u32 pack2(float a, float b) {
    return (u32)f2bf(a) | ((u32)f2bf(b) << 16);
}

// 16-lane (row) sum reduction via DPP: bitwise-identical to xor-butterfly m=1,2,4,8.
template <int CTRL>
static __device__ __forceinline__ float dpp_addf(float x) {
    int y = __builtin_amdgcn_update_dpp(0, __float_as_int(x), CTRL, 0xF, 0xF, false);
    return x + __int_as_float(y);
}
static __device__ __forceinline__ float row_red16(float s) {
    s = dpp_addf<0xB1>(s);    // quad_perm [1,0,3,2]  == xor 1
    s = dpp_addf<0x4E>(s);    // quad_perm [2,3,0,1]  == xor 2
    s = dpp_addf<0x141>(s);   // row_half_mirror      == xor 4 (post quad-sum)
    s = dpp_addf<0x140>(s);   // row_mirror           == xor 8 (post half-sum)
    return s;
}

static __device__ __forceinline__ f32x4_t mfma_16x16x16(bf16x4_t a, bf16x4_t b, f32x4_t c) {
#if __has_builtin(__builtin_amdgcn_mfma_f32_16x16x16bf16_1k)
    return __builtin_amdgcn_mfma_f32_16x16x16bf16_1k(a, b, c, 0, 0, 0);
#else
    f32x4_t d;
    asm("v_mfma_f32_16x16x16_bf16 %0, %1, %2, %3" : "=v"(d) : "v"(a), "v"(b), "v"(c));
    return d;
#endif
}

// ---------------- K0: cast weights to bf16; wvln = w_ln @ w_v; bias2 = w_ln@b_v + b_ln
__global__ void k0_prep(const float* __restrict__ w_qkv, const float* __restrict__ b_qkv,
                        const float* __restrict__ w_ln, const float* __restrict__ b_ln,
                        u16* __restrict__ w_kv_bf, u16* __restrict__ w_q_bf,
                        u16* __restrict__ wvln_bf, float* __restrict__ bias2) {
    int idx = blockIdx.x * 256 + threadIdx.x;
    if (idx < 8192) {                       // rows 64..191 of w_qkv = [w_k | w_v]
        w_kv_bf[idx] = f2bf(w_qkv[4096 + idx]);
    } else if (idx < 12288) {               // rows 0..63 = w_q
        w_q_bf[idx - 8192] = f2bf(w_qkv[idx - 8192]);
    } else if (idx < 16384) {
        int i = idx - 12288; int d = i >> 6, c = i & 63;
        float s = 0.f;
        #pragma unroll 8
        for (int e = 0; e < 64; ++e)
            s += w_ln[d * 64 + e] * w_qkv[(128 + e) * 64 + c];
        wvln_bf[i] = f2bf(s);
    } else if (idx < 16448) {
        int d = idx - 16384;
        float s = b_ln[d];
        #pragma unroll 8
        for (int e = 0; e < 64; ++e)
            s += w_ln[d * 64 + e] * b_qkv[128 + e];
        bias2[d] = s;
    }
}

// ---------------- K1: per (g,b): loop n-tiles of 64; bf16 double-buffered x staging;
// MFMA k|v GEMM; DPP stats; in-register kvu via 16x16x16 MFMA (per-wave n-slice);
// cross-wave reduce + flush at end. One barrier per tile.
__global__ __launch_bounds__(256, 3) void k1_kv(const float* __restrict__ x,
        const u16* __restrict__ w_kv_bf, const float* __restrict__ b_qkv,
        float* __restrict__ kvu_part, float* __restrict__ ksq_part) {
    __shared__ u16 xsb[2][64 * SXB];    // x tiles bf16: [c][n], double-buffered
    __shared__ float red[4][16][64];    // cross-wave kvu reduction (flush only)
    __shared__ float ksq_red[4][64];
    const int tid = threadIdx.x;
    const int w = tid >> 6, lane = tid & 63, q = lane >> 4, l15 = lane & 15;
    const int b = blockIdx.y, g = blockIdx.x;
    const float* xb = x + (size_t)b * 64 * NN;
    const int sc = tid >> 4;          // staging channel (+16*i)
    const int sn = (tid & 15) << 2;   // staging n offset (float4)
    const float* xg = xb + (size_t)sc * NN + sn;

    float bias[8];
    #pragma unroll
    for (int t8 = 0; t8 < 8; ++t8) bias[t8] = b_qkv[64 + 16 * t8 + l15];

    f32x4_t accK[4][4];   // kvu: [c-tile][e-tile], wave-local over its 16-n slices
    #pragma unroll
    for (int t4 = 0; t4 < 4; ++t4)
        #pragma unroll
        for (int et = 0; et < 4; ++et) accK[t4][et] = (f32x4_t){0.f, 0.f, 0.f, 0.f};
    float ksq_acc[4] = {0.f, 0.f, 0.f, 0.f};

    // prefetch first tile into registers
    float4 pf[4];
    #pragma unroll
    for (int i = 0; i < 4; ++i)
        pf[i] = *(const float4*)(xg + (size_t)(16 * i) * NN + g * 64);

    int p = 0;
    for (int t = g; t < NN / 64; t += G1) {
        // ---- commit prefetched tile to LDS as bf16 (convert once at stage)
        u16* xp = xsb[p];
        #pragma unroll
        for (int i = 0; i < 4; ++i) {
            int c = 16 * i + sc;
            uint2 pk;
            pk.x = pack2(pf[i].x, pf[i].y);
            pk.y = pack2(pf[i].z, pf[i].w);
            *(uint2*)&xp[c * SXB + sn] = pk;
        }
        __syncthreads();   // single barrier per tile (xs double-buffered)
        // ---- issue next tile's loads; latency hides under compute below
        if (t + G1 < NN / 64) {
            #pragma unroll
            for (int i = 0; i < 4; ++i)
                pf[i] = *(const float4*)(xg + (size_t)(16 * i) * NN + (t + G1) * 64);
        }
        // ---- GEMM A: D[n][dcol], dcol 0..63 = k, 64..127 = v (K = 64 channels)
        f32x4_t accA[8];
        #pragma unroll
        for (int t8 = 0; t8 < 8; ++t8)
            accA[t8] = (f32x4_t){bias[t8], bias[t8], bias[t8], bias[t8]};
        #pragma unroll
        for (int ks = 0; ks < 2; ++ks) {
            union { u16 u[8]; bf16x8_t v; } af;   // x^T[n][c] frag, bf16 direct
            #pragma unroll
            for (int j = 0; j < 8; ++j)
                af.u[j] = xp[(ks * 32 + q * 8 + j) * SXB + 16 * w + l15];
            #pragma unroll
            for (int t8 = 0; t8 < 8; ++t8) {
                bf16x8_t bf = *(const bf16x8_t*)(w_kv_bf + (16 * t8 + l15) * 64 + ks * 32 + q * 8);
                accA[t8] = __builtin_amdgcn_mfma_f32_16x16x32_bf16(af.v, bf, accA[t8], 0, 0, 0);
            }
        }
        // ---- k stats per row (row = 4q + r): mean, 1/(k2s+eps) via DPP row reductions
        float mu[4], rin[4];
        #pragma unroll
        for (int r = 0; r < 4; ++r) {
            float a0 = accA[0][r], a1 = accA[1][r], a2 = accA[2][r], a3 = accA[3][r];
            float s1 = row_red16(a0 + a1 + a2 + a3);
            float s2 = row_red16(a0 * a0 + a1 * a1 + a2 * a2 + a3 * a3);
            mu[r] = s1 * 0.015625f;
            rin[r] = 1.f / (s2 - 64.f * mu[r] * mu[r] + 1e-7f);
        }
        // ---- k2t, v -> in-register bf16 fragments (accA layout == 16x16x16 operand layout)
        union { bf16x4_t v; uint2 h; } ka[4], vb[4];
        #pragma unroll
        for (int t4 = 0; t4 < 4; ++t4) {
            float t2v[4];
            #pragma unroll
            for (int r = 0; r < 4; ++r) {
                float d = accA[t4][r] - mu[r];
                float t2 = d * d * rin[r];
                t2v[r] = t2;
                ksq_acc[t4] += t2 * t2;
            }
            ka[t4].h.x = pack2(t2v[0], t2v[1]);
            ka[t4].h.y = pack2(t2v[2], t2v[3]);
        }
        #pragma unroll
        for (int et = 0; et < 4; ++et) {
            vb[et].h.x = pack2(accA[4 + et][0], accA[4 + et][1]);
            vb[et].h.y = pack2(accA[4 + et][2], accA[4 + et][3]);
        }
        // ---- kvu: D[c][e] += sum_{n in wave slice} k2t[n][c]*v[n][e], all in registers
        #pragma unroll
        for (int t4 = 0; t4 < 4; ++t4)
            #pragma unroll
            for (int et = 0; et < 4; ++et)
                accK[t4][et] = mfma_16x16x16(ka[t4].v, vb[et].v, accK[t4][et]);
        p ^= 1;
    }
    // ---- flush: cross-wave reduce kvu via LDS, then per-block partials to global
    float* kp = kvu_part + (size_t)(b * G1 + g) * 4096;
    #pragma unroll
    for (int t4 = 0; t4 < 4; ++t4) {
        __syncthreads();
        #pragma unroll
        for (int et = 0; et < 4; ++et)
            #pragma unroll
            for (int r = 0; r < 4; ++r)
                red[w][4 * q + r][16 * et + l15] = accK[t4][et][r];
        __syncthreads();
        #pragma unroll
        for (int l = 0; l < 4; ++l) {
            int idx = tid + 256 * l; int cl = idx >> 6, e = idx & 63;
            kp[(16 * t4 + cl) * 64 + e] =
                red[0][cl][e] + red[1][cl][e] + red[2][cl][e] + red[3][cl][e];
        }
    }
    #pragma unroll
    for (int t4 = 0; t4 < 4; ++t4) {
        float v = ksq_acc[t4];
        v += __shfl_xor(v, 16, 64);
        v += __shfl_xor(v, 32, 64);
        if (q == 0) ksq_red[w][16 * t4 + l15] = v;
    }
    __syncthreads();
    if (tid < 64)
        ksq_part[(size_t)(b * G1 + g) * 64 + tid] =
            ksq_red[0][tid] + ksq_red[1][tid] + ksq_red[2][tid] + ksq_red[3][tid];
}

// ---------------- K2: reduce partials over g; kvw_t[b][d][c] = bf16(inv_k[c]*sum_e kvu[c][e]*w_ln[d][e])
// (unchanged)
__global__ __launch_bounds__(256) void k2_kvw(const float* __restrict__ kvu_part,
        const float* __restrict__ ksq_part, const float* __restrict__ w_ln,
        u16* __restrict__ kvw_t) {
    __shared__ float wln_s[64 * 68];
    __shared__ float kvr[4 * 68];
    __shared__ float ksq_r[64];
    __shared__ float inv_k[4];
    const int tid = threadIdx.x;
    const int c0 = blockIdx.x * 4, b = blockIdx.y;
    #pragma unroll
    for (int lidx = 0; lidx < 16; ++lidx) {
        int idx = tid + 256 * lidx;
        wln_s[(idx >> 6) * 68 + (idx & 63)] = w_ln[idx];
    }
    {   // thread (cl = tid>>6, e = tid&63): sum kvu over g, 8 concurrent chains
        const int cl = tid >> 6, e = tid & 63;
        const float* p = kvu_part + (size_t)b * G1 * 4096 + (c0 + cl) * 64 + e;
        float s[8];
        #pragma unroll
        for (int k = 0; k < 8; ++k) s[k] = 0.f;
        for (int g = 0; g < G1; g += 8) {
            #pragma unroll
            for (int k = 0; k < 8; ++k) s[k] += p[(size_t)(g + k) * 4096];
        }
        kvr[cl * 68 + e] = ((s[0] + s[1]) + (s[2] + s[3])) + ((s[4] + s[5]) + (s[6] + s[7]));
    }
    if (tid < 64) {  // ksq reduce spread over 16 g-partials x 4 c
        const int cl = tid & 3, gp = tid >> 2;
        float s = 0.f;
        #pragma unroll
        for (int k = 0; k < 6; ++k)
            s += ksq_part[(size_t)(b * G1 + gp + 16 * k) * 64 + c0 + cl];
        ksq_r[tid] = s;
    }
    __syncthreads();
    if (tid < 4) {
        float s = 0.f;
        #pragma unroll
        for (int gp = 0; gp < 16; ++gp) s += ksq_r[gp * 4 + tid];
        inv_k[tid] = 1.f / (fmaxf(sqrtf(s), 1e-12f) * 256.f);
    }
    __syncthreads();
    {   // thread (d = tid>>2, cl = tid&3): 64-wide dot, vectorized
        const int d = tid >> 2, cl = tid & 3;
        float s = 0.f;
        #pragma unroll
        for (int e4 = 0; e4 < 16; ++e4) {
            float4 a  = *(const float4*)&kvr[cl * 68 + 4 * e4];
            float4 wv = *(const float4*)&wln_s[d * 68 + 4 * e4];
            s += a.x * wv.x + a.y * wv.y + a.z * wv.z + a.w * wv.w;
        }
        kvw_t[(size_t)b * 4096 + d * 64 + c0 + cl] = f2bf(s * inv_k[cl]);
    }
}

// ---------------- K3: persistent multi-tile; bf16 double-buffered staging; DPP stats;
// operand-swapped d-major o/t2 GEMMs; direct register->global stores. One barrier/tile
// (qt + wrow are same-wave-only: lgkmcnt dependency, no cross-wave hazard).
__global__ __launch_bounds__(256) void k3_out(const float* __restrict__ x,
        const u16* __restrict__ w_q_bf, const u16* __restrict__ wvln_bf,
        const float* __restrict__ b_qkv, const float* __restrict__ bias2,
        const u16* __restrict__ kvw_t, float* __restrict__ out) {
    __shared__ u16 xsb[2][64 * SXB];   // x tiles bf16: [c][n], double-buffered
    __shared__ u16 qt[64 * STK];       // q2: [n][c] bf16 (same-wave rows only)
    __shared__ float wrow_s[4][16];    // per-wave w_row redistribution
    const int tid = threadIdx.x;
    const int w = tid >> 6, lane = tid & 63, q = lane >> 4, l15 = lane & 15;
    const int b = blockIdx.y, g = blockIdx.x;
    const float* xb = x + (size_t)b * 64 * NN;
    const int sc = tid >> 4, sn = (tid & 15) << 2;
    const float* xg = xb + (size_t)sc * NN + sn;
    const u16* kvb = kvw_t + (size_t)b * 4096;

    float biasQ[4];
    #pragma unroll
    for (int t4 = 0; t4 < 4; ++t4) biasQ[t4] = b_qkv[16 * t4 + l15];
    float biasO[4][4];   // bias2[d] for d = 16*dt + 4*q + r (d-major accO init)
    #pragma unroll
    for (int dt = 0; dt < 4; ++dt)
        #pragma unroll
        for (int r = 0; r < 4; ++r) biasO[dt][r] = bias2[16 * dt + 4 * q + r];

    // prefetch first tile into registers
    float4 pf[4];
    #pragma unroll
    for (int i = 0; i < 4; ++i)
        pf[i] = *(const float4*)(xg + (size_t)(16 * i) * NN + g * 64);

    int p = 0;
    for (int t = g; t < NN / 64; t += G3) {
        const int n0 = t * 64;
        // ---- commit prefetched tile to LDS as bf16
        u16* xp = xsb[p];
        #pragma unroll
        for (int i = 0; i < 4; ++i) {
            int c = 16 * i + sc;
            uint2 pk;
            pk.x = pack2(pf[i].x, pf[i].y);
            pk.y = pack2(pf[i].z, pf[i].w);
            *(uint2*)&xp[c * SXB + sn] = pk;
        }
        __syncthreads();   // single barrier per tile
        if (t + G3 < NN / 64) {
            #pragma unroll
            for (int i = 0; i < 4; ++i)
                pf[i] = *(const float4*)(xg + (size_t)(16 * i) * NN + (t + G3) * 64);
        }
        // ---- GEMM A: accQ = q (n-major, for stats); accO = o = x@wvln^T + bias2 (d-major)
        f32x4_t accQ[4], accO[4];
        #pragma unroll
        for (int t4 = 0; t4 < 4; ++t4)
            accQ[t4] = (f32x4_t){biasQ[t4], biasQ[t4], biasQ[t4], biasQ[t4]};
        #pragma unroll
        for (int dt = 0; dt < 4; ++dt)
            accO[dt] = (f32x4_t){biasO[dt][0], biasO[dt][1], biasO[dt][2], biasO[dt][3]};
        #pragma unroll
        for (int ks = 0; ks < 2; ++ks) {
            union { u16 u[8]; bf16x8_t v; } af;   // x^T[n][c] frag, bf16 direct
            #pragma unroll
            for (int j = 0; j < 8; ++j)
                af.u[j] = xp[(ks * 32 + q * 8 + j) * SXB + 16 * w + l15];
            #pragma unroll
            for (int t4 = 0; t4 < 4; ++t4) {
                bf16x8_t bq = *(const bf16x8_t*)(w_q_bf + (16 * t4 + l15) * 64 + ks * 32 + q * 8);
                accQ[t4] = __builtin_amdgcn_mfma_f32_16x16x32_bf16(af.v, bq, accQ[t4], 0, 0, 0);
            }
            #pragma unroll
            for (int dt = 0; dt < 4; ++dt) {
                bf16x8_t aw = *(const bf16x8_t*)(wvln_bf + (16 * dt + l15) * 64 + ks * 32 + q * 8);
                accO[dt] = __builtin_amdgcn_mfma_f32_16x16x32_bf16(aw, af.v, accO[dt], 0, 0, 0);
            }
        }
        // ---- q stats via DPP: mu, q2s; q2; w_row = 1/max(||q2||, 1e-12*(q2s+eps))
        float mu[4], q2s[4];
        #pragma unroll
        for (int r = 0; r < 4; ++r) {
            float a0 = accQ[0][r], a1 = accQ[1][r], a2 = accQ[2][r], a3 = accQ[3][r];
            float s1 = row_red16(a0 + a1 + a2 + a3);
            float s2 = row_red16(a0 * a0 + a1 * a1 + a2 * a2 + a3 * a3);
            mu[r] = s1 * 0.015625f;
            q2s[r] = s2 - 64.f * mu[r] * mu[r];
        }
        float q2v[4][4];
        float s4[4] = {0.f, 0.f, 0.f, 0.f};
        #pragma unroll
        for (int t4 = 0; t4 < 4; ++t4)
            #pragma unroll
            for (int r = 0; r < 4; ++r) {
                float d = accQ[t4][r] - mu[r];
                float v2 = d * d;
                q2v[t4][r] = v2;
                s4[r] += v2 * v2;
            }
        float w_row[4];
        #pragma unroll
        for (int r = 0; r < 4; ++r) {
            float s = row_red16(s4[r]);
            w_row[r] = 1.f / fmaxf(sqrtf(s), 1e-12f * (q2s[r] + 1e-7f));
        }
        // ---- redistribute w_row: row n=16w+4q+r -> lane col l15 (same wave only)
        if (l15 == 0) {
            #pragma unroll
            for (int r = 0; r < 4; ++r) wrow_s[w][4 * q + r] = w_row[r];
        }
        // ---- q2 -> qt LDS ([n][c] bf16, same-wave rows)
        #pragma unroll
        for (int t4 = 0; t4 < 4; ++t4)
            #pragma unroll
            for (int r = 0; r < 4; ++r)
                qt[(16 * w + 4 * q + r) * STK + 16 * t4 + l15] = f2bf(q2v[t4][r]);
        // ---- GEMM B (d-major): t2[d][n] = sum_c kvw[d][c]-frag * q2[n][c]
        f32x4_t accB[4];
        #pragma unroll
        for (int dt = 0; dt < 4; ++dt) accB[dt] = (f32x4_t){0.f, 0.f, 0.f, 0.f};
        #pragma unroll
        for (int ks = 0; ks < 2; ++ks) {
            union { bf16x8_t v; uint2 h[2]; } b2;   // q2[n][c] frag as B-operand
            const u16* bp = &qt[(16 * w + l15) * STK + ks * 32 + q * 8];
            b2.h[0] = *(const uint2*)bp;
            b2.h[1] = *(const uint2*)(bp + 4);
            #pragma unroll
            for (int dt = 0; dt < 4; ++dt) {
                bf16x8_t ak = *(const bf16x8_t*)(kvb + (16 * dt + l15) * 64 + ks * 32 + q * 8);
                accB[dt] = __builtin_amdgcn_mfma_f32_16x16x32_bf16(ak, b2.v, accB[dt], 0, 0, 0);
            }
        }
        float wr = wrow_s[w][l15];
        // ---- epilogue: out[d][n] = o + w_row[n]*t2, direct register stores
        #pragma unroll
        for (int dt = 0; dt < 4; ++dt) {
            float* op = out + ((size_t)(b * 64 + 16 * dt + 4 * q)) * NN + n0 + 16 * w + l15;
            #pragma unroll
            for (int r = 0; r < 4; ++r)
                op[(size_t)r * NN] = accO[dt][r] + wr * accB[dt][r];
        }
        p ^= 1;
    }
}

extern "C" void kernel_launch(void* const* d_in, const int* in_sizes, int n_in,
                              void* d_out, int out_size, void* d_ws, size_t ws_size,
                              hipStream_t stream) {
    const float* x     = (const float*)d_in[0];
    const float* w_qkv = (const float*)d_in[1];
    const float* b_qkv = (const float*)d_in[2];
    const float* w_ln  = (const float*)d_in[3];
    const float* b_ln  = (const float*)d_in[4];
    float* out = (float*)d_out;
    char* ws = (char*)d_ws;
    // byte layout (total 12.88 MB, unchanged)
    float* kvu_part = (float*)(ws);                       // 8*96*4096 f32
    float* ksq_part = (float*)(ws + 12582912);            // 8*96*64 f32
    u16*   kvw_t    = (u16*)  (ws + 12779520);            // 8*4096 bf16
    u16*   w_kv_bf  = (u16*)  (ws + 12845056);            // 128*64 bf16
    u16*   w_q_bf   = (u16*)  (ws + 12861440);            // 64*64 bf16
    u16*   wvln_bf  = (u16*)  (ws + 12869632);            // 64*64 bf16
    float* bias2    = (float*)(ws + 12877824);            // 64 f32

    k0_prep<<<dim3(65), dim3(256), 0, stream>>>(w_qkv, b_qkv, w_ln, b_ln,
                                                w_kv_bf, w_q_bf, wvln_bf, bias2);
    k1_kv<<<dim3(G1, 8), dim3(256), 0, stream>>>(x, w_kv_bf, b_qkv, kvu_part, ksq_part);
    k2_kvw<<<dim3(16, 8), dim3(256), 0, stream>>>(kvu_part, ksq_part, w_ln, kvw_t);
    k3_out<<<dim3(G3, 8), dim3(256), 0, stream>>>(x, w_q_bf, wvln_bf, b_qkv, bias2, kvw_t, out);
}

// Round 6
// 302.498 us; speedup vs baseline: 1.1939x; 1.1939x over previous
//
#include <hip/hip_runtime.h>

// ESSAttn bf16-MFMA version. b=8, C=64, H=W=256 (N=65536), fp32 in/out.
// Math (exact refactor of reference):
//   out[b,n,d] = x_col(n)@wvln[d,:] + bias2[d] + w_row[n] * sum_c q2[n,c]*kvw[b][c][d]
//   kvw[c][d]  = inv_k[c] * sum_e kvu[c][e]*w_ln[d][e],  inv_k = 1/(256*max(sqrt(ksq_c),1e-12))
//   kvu[c][e]  = sum_n k2t[n,c]*v[n,e],  ksq_c = sum_n k2t^2
//   k2t = (k-mean_c(k))^2/(k2s+1e-7),  q2 = (q-mean)^2, w_row folds q2 normalizations.
// Round 6: round-5 structure with the spill bug fixed. R5's __launch_bounds__(256,3)
// capped regs at ~128 while the in-register kvu needs ~150 -> scratch spill (FETCH 351MB,
// WRITE 68MB, k1 83->134us). Fix: plain __launch_bounds__(256) (no min-waves cap) +
// __builtin_bit_cast for bf16 fragment packing (no union memory round-trip).

typedef unsigned short u16;
typedef unsigned int u32;
typedef short bf16x8_t __attribute__((ext_vector_type(8)));
typedef short bf16x4_t __attribute__((ext_vector_type(4)));
typedef float f32x4_t __attribute__((ext_vector_type(4)));

#define NN 65536
#define G1 96
#define G3 192   // k3 persistent blocks per batch
#define STK 68   // bf16 qt LDS stride (elements)
#define SXB 68   // bf16 x-tile LDS stride (mult of 4 -> b64-aligned packed writes)

static __device__ __forceinline__ u16 f2bf(float f) {
    union { float f; u32 u; } v; v.f = f;
    u32 r = v.u + 0x7FFFu + ((v.u >> 16) & 1u);
    return (u16)(r >> 16);
}
static __device__ __forceinline__ u32 pack2(float a, float b) {
    return (u32)f2bf(a) | ((u32)f2bf(b) << 16);
}
static __device__ __forceinline__ bf16x4_t pack4(float a, float b, float c, float d) {
    uint2 t; t.x = pack2(a, b); t.y = pack2(c, d);
    return __builtin_bit_cast(bf16x4_t, t);
}

// 16-lane (row) sum reduction via DPP: bitwise-identical to xor-butterfly m=1,2,4,8.
template <int CTRL>
static __device__ __forceinline__ float dpp_addf(float x) {
    int y = __builtin_amdgcn_update_dpp(0, __float_as_int(x), CTRL, 0xF, 0xF, false);
    return x + __int_as_float(y);
}
static __device__ __forceinline__ float row_red16(float s) {
    s = dpp_addf<0xB1>(s);    // quad_perm [1,0,3,2]  == xor 1
    s = dpp_addf<0x4E>(s);    // quad_perm [2,3,0,1]  == xor 2
    s = dpp_addf<0x141>(s);   // row_half_mirror      == xor 4 (post quad-sum)
    s = dpp_addf<0x140>(s);   // row_mirror           == xor 8 (post half-sum)
    return s;
}

static __device__ __forceinline__ f32x4_t mfma_16x16x16(bf16x4_t a, bf16x4_t b, f32x4_t c) {
#if __has_builtin(__builtin_amdgcn_mfma_f32_16x16x16bf16_1k)
    return __builtin_amdgcn_mfma_f32_16x16x16bf16_1k(a, b, c, 0, 0, 0);
#else
    f32x4_t d;
    asm("v_mfma_f32_16x16x16_bf16 %0, %1, %2, %3" : "=v"(d) : "v"(a), "v"(b), "v"(c));
    return d;
#endif
}

// ---------------- K0: cast weights to bf16; wvln = w_ln @ w_v; bias2 = w_ln@b_v + b_ln
__global__ void k0_prep(const float* __restrict__ w_qkv, const float* __restrict__ b_qkv,
                        const float* __restrict__ w_ln, const float* __restrict__ b_ln,
                        u16* __restrict__ w_kv_bf, u16* __restrict__ w_q_bf,
                        u16* __restrict__ wvln_bf, float* __restrict__ bias2) {
    int idx = blockIdx.x * 256 + threadIdx.x;
    if (idx < 8192) {                       // rows 64..191 of w_qkv = [w_k | w_v]
        w_kv_bf[idx] = f2bf(w_qkv[4096 + idx]);
    } else if (idx < 12288) {               // rows 0..63 = w_q
        w_q_bf[idx - 8192] = f2bf(w_qkv[idx - 8192]);
    } else if (idx < 16384) {
        int i = idx - 12288; int d = i >> 6, c = i & 63;
        float s = 0.f;
        #pragma unroll 8
        for (int e = 0; e < 64; ++e)
            s += w_ln[d * 64 + e] * w_qkv[(128 + e) * 64 + c];
        wvln_bf[i] = f2bf(s);
    } else if (idx < 16448) {
        int d = idx - 16384;
        float s = b_ln[d];
        #pragma unroll 8
        for (int e = 0; e < 64; ++e)
            s += w_ln[d * 64 + e] * b_qkv[128 + e];
        bias2[d] = s;
    }
}

// ---------------- K1: per (g,b): loop n-tiles of 64; bf16 double-buffered x staging;
// MFMA k|v GEMM; DPP stats; in-register kvu via 16x16x16 MFMA (per-wave n-slice);
// cross-wave reduce + flush at end. One barrier per tile. NO min-waves bound (regs free).
__global__ __launch_bounds__(256) void k1_kv(const float* __restrict__ x,
        const u16* __restrict__ w_kv_bf, const float* __restrict__ b_qkv,
        float* __restrict__ kvu_part, float* __restrict__ ksq_part) {
    __shared__ u16 xsb[2][64 * SXB];    // x tiles bf16: [c][n], double-buffered
    __shared__ float red[4][16][64];    // cross-wave kvu reduction (flush only)
    __shared__ float ksq_red[4][64];
    const int tid = threadIdx.x;
    const int w = tid >> 6, lane = tid & 63, q = lane >> 4, l15 = lane & 15;
    const int b = blockIdx.y, g = blockIdx.x;
    const float* xb = x + (size_t)b * 64 * NN;
    const int sc = tid >> 4;          // staging channel (+16*i)
    const int sn = (tid & 15) << 2;   // staging n offset (float4)
    const float* xg = xb + (size_t)sc * NN + sn;

    float bias[8];
    #pragma unroll
    for (int t8 = 0; t8 < 8; ++t8) bias[t8] = b_qkv[64 + 16 * t8 + l15];

    f32x4_t accK[4][4];   // kvu: [c-tile][e-tile], wave-local over its 16-n slices
    #pragma unroll
    for (int t4 = 0; t4 < 4; ++t4)
        #pragma unroll
        for (int et = 0; et < 4; ++et) accK[t4][et] = (f32x4_t){0.f, 0.f, 0.f, 0.f};
    float ksq_acc[4] = {0.f, 0.f, 0.f, 0.f};

    // prefetch first tile into registers
    float4 pf[4];
    #pragma unroll
    for (int i = 0; i < 4; ++i)
        pf[i] = *(const float4*)(xg + (size_t)(16 * i) * NN + g * 64);

    int p = 0;
    for (int t = g; t < NN / 64; t += G1) {
        // ---- commit prefetched tile to LDS as bf16 (convert once at stage)
        u16* xp = xsb[p];
        #pragma unroll
        for (int i = 0; i < 4; ++i) {
            int c = 16 * i + sc;
            uint2 pk;
            pk.x = pack2(pf[i].x, pf[i].y);
            pk.y = pack2(pf[i].z, pf[i].w);
            *(uint2*)&xp[c * SXB + sn] = pk;
        }
        __syncthreads();   // single barrier per tile (xs double-buffered)
        // ---- issue next tile's loads; latency hides under compute below
        if (t + G1 < NN / 64) {
            #pragma unroll
            for (int i = 0; i < 4; ++i)
                pf[i] = *(const float4*)(xg + (size_t)(16 * i) * NN + (t + G1) * 64);
        }
        // ---- GEMM A: D[n][dcol], dcol 0..63 = k, 64..127 = v (K = 64 channels)
        f32x4_t accA[8];
        #pragma unroll
        for (int t8 = 0; t8 < 8; ++t8)
            accA[t8] = (f32x4_t){bias[t8], bias[t8], bias[t8], bias[t8]};
        #pragma unroll
        for (int ks = 0; ks < 2; ++ks) {
            union { u16 u[8]; bf16x8_t v; } af;   // x^T[n][c] frag, bf16 direct
            #pragma unroll
            for (int j = 0; j < 8; ++j)
                af.u[j] = xp[(ks * 32 + q * 8 + j) * SXB + 16 * w + l15];
            #pragma unroll
            for (int t8 = 0; t8 < 8; ++t8) {
                bf16x8_t bf = *(const bf16x8_t*)(w_kv_bf + (16 * t8 + l15) * 64 + ks * 32 + q * 8);
                accA[t8] = __builtin_amdgcn_mfma_f32_16x16x32_bf16(af.v, bf, accA[t8], 0, 0, 0);
            }
        }
        // ---- k stats per row (row = 4q + r): mean, 1/(k2s+eps) via DPP row reductions
        float mu[4], rin[4];
        #pragma unroll
        for (int r = 0; r < 4; ++r) {
            float a0 = accA[0][r], a1 = accA[1][r], a2 = accA[2][r], a3 = accA[3][r];
            float s1 = row_red16(a0 + a1 + a2 + a3);
            float s2 = row_red16(a0 * a0 + a1 * a1 + a2 * a2 + a3 * a3);
            mu[r] = s1 * 0.015625f;
            rin[r] = 1.f / (s2 - 64.f * mu[r] * mu[r] + 1e-7f);
        }
        // ---- k2t, v -> in-register bf16 fragments (accA layout == 16x16x16 operand layout)
        bf16x4_t ka[4], vb[4];
        #pragma unroll
        for (int t4 = 0; t4 < 4; ++t4) {
            float t2v[4];
            #pragma unroll
            for (int r = 0; r < 4; ++r) {
                float d = accA[t4][r] - mu[r];
                float t2 = d * d * rin[r];
                t2v[r] = t2;
                ksq_acc[t4] += t2 * t2;
            }
            ka[t4] = pack4(t2v[0], t2v[1], t2v[2], t2v[3]);
        }
        #pragma unroll
        for (int et = 0; et < 4; ++et)
            vb[et] = pack4(accA[4 + et][0], accA[4 + et][1], accA[4 + et][2], accA[4 + et][3]);
        // ---- kvu: D[c][e] += sum_{n in wave slice} k2t[n][c]*v[n][e], all in registers
        #pragma unroll
        for (int t4 = 0; t4 < 4; ++t4)
            #pragma unroll
            for (int et = 0; et < 4; ++et)
                accK[t4][et] = mfma_16x16x16(ka[t4], vb[et], accK[t4][et]);
        p ^= 1;
    }
    // ---- flush: cross-wave reduce kvu via LDS, then per-block partials to global
    float* kp = kvu_part + (size_t)(b * G1 + g) * 4096;
    #pragma unroll
    for (int t4 = 0; t4 < 4; ++t4) {
        __syncthreads();
        #pragma unroll
        for (int et = 0; et < 4; ++et)
            #pragma unroll
            for (int r = 0; r < 4; ++r)
                red[w][4 * q + r][16 * et + l15] = accK[t4][et][r];
        __syncthreads();
        #pragma unroll
        for (int l = 0; l < 4; ++l) {
            int idx = tid + 256 * l; int cl = idx >> 6, e = idx & 63;
            kp[(16 * t4 + cl) * 64 + e] =
                red[0][cl][e] + red[1][cl][e] + red[2][cl][e] + red[3][cl][e];
        }
    }
    #pragma unroll
    for (int t4 = 0; t4 < 4; ++t4) {
        float v = ksq_acc[t4];
        v += __shfl_xor(v, 16, 64);
        v += __shfl_xor(v, 32, 64);
        if (q == 0) ksq_red[w][16 * t4 + l15] = v;
    }
    __syncthreads();
    if (tid < 64)
        ksq_part[(size_t)(b * G1 + g) * 64 + tid] =
            ksq_red[0][tid] + ksq_red[1][tid] + ksq_red[2][tid] + ksq_red[3][tid];
}

// ---------------- K2: reduce partials over g; kvw_t[b][d][c] = bf16(inv_k[c]*sum_e kvu[c][e]*w_ln[d][e])
// (unchanged)
__global__ __launch_bounds__(256) void k2_kvw(const float* __restrict__ kvu_part,
        const float* __restrict__ ksq_part, const float* __restrict__ w_ln,
        u16* __restrict__ kvw_t) {
    __shared__ float wln_s[64 * 68];
    __shared__ float kvr[4 * 68];
    __shared__ float ksq_r[64];
    __shared__ float inv_k[4];
    const int tid = threadIdx.x;
    const int c0 = blockIdx.x * 4, b = blockIdx.y;
    #pragma unroll
    for (int lidx = 0; lidx < 16; ++lidx) {
        int idx = tid + 256 * lidx;
        wln_s[(idx >> 6) * 68 + (idx & 63)] = w_ln[idx];
    }
    {   // thread (cl = tid>>6, e = tid&63): sum kvu over g, 8 concurrent chains
        const int cl = tid >> 6, e = tid & 63;
        const float* p = kvu_part + (size_t)b * G1 * 4096 + (c0 + cl) * 64 + e;
        float s[8];
        #pragma unroll
        for (int k = 0; k < 8; ++k) s[k] = 0.f;
        for (int g = 0; g < G1; g += 8) {
            #pragma unroll
            for (int k = 0; k < 8; ++k) s[k] += p[(size_t)(g + k) * 4096];
        }
        kvr[cl * 68 + e] = ((s[0] + s[1]) + (s[2] + s[3])) + ((s[4] + s[5]) + (s[6] + s[7]));
    }
    if (tid < 64) {  // ksq reduce spread over 16 g-partials x 4 c
        const int cl = tid & 3, gp = tid >> 2;
        float s = 0.f;
        #pragma unroll
        for (int k = 0; k < 6; ++k)
            s += ksq_part[(size_t)(b * G1 + gp + 16 * k) * 64 + c0 + cl];
        ksq_r[tid] = s;
    }
    __syncthreads();
    if (tid < 4) {
        float s = 0.f;
        #pragma unroll
        for (int gp = 0; gp < 16; ++gp) s += ksq_r[gp * 4 + tid];
        inv_k[tid] = 1.f / (fmaxf(sqrtf(s), 1e-12f) * 256.f);
    }
    __syncthreads();
    {   // thread (d = tid>>2, cl = tid&3): 64-wide dot, vectorized
        const int d = tid >> 2, cl = tid & 3;
        float s = 0.f;
        #pragma unroll
        for (int e4 = 0; e4 < 16; ++e4) {
            float4 a  = *(const float4*)&kvr[cl * 68 + 4 * e4];
            float4 wv = *(const float4*)&wln_s[d * 68 + 4 * e4];
            s += a.x * wv.x + a.y * wv.y + a.z * wv.z + a.w * wv.w;
        }
        kvw_t[(size_t)b * 4096 + d * 64 + c0 + cl] = f2bf(s * inv_k[cl]);
    }
}

// ---------------- K3: persistent multi-tile; bf16 double-buffered staging; DPP stats;
// operand-swapped d-major o/t2 GEMMs; direct register->global stores. One barrier/tile
// (qt + wrow are same-wave-only: lgkmcnt dependency, no cross-wave hazard).
__global__ __launch_bounds__(256) void k3_out(const float* __restrict__ x,
        const u16* __restrict__ w_q_bf, const u16* __restrict__ wvln_bf,
        const float* __restrict__ b_qkv, const float* __restrict__ bias2,
        const u16* __restrict__ kvw_t, float* __restrict__ out) {
    __shared__ u16 xsb[2][64 * SXB];   // x tiles bf16: [c][n], double-buffered
    __shared__ u16 qt[64 * STK];       // q2: [n][c] bf16 (same-wave rows only)
    __shared__ float wrow_s[4][16];    // per-wave w_row redistribution
    const int tid = threadIdx.x;
    const int w = tid >> 6, lane = tid & 63, q = lane >> 4, l15 = lane & 15;
    const int b = blockIdx.y, g = blockIdx.x;
    const float* xb = x + (size_t)b * 64 * NN;
    const int sc = tid >> 4, sn = (tid & 15) << 2;
    const float* xg = xb + (size_t)sc * NN + sn;
    const u16* kvb = kvw_t + (size_t)b * 4096;

    float biasQ[4];
    #pragma unroll
    for (int t4 = 0; t4 < 4; ++t4) biasQ[t4] = b_qkv[16 * t4 + l15];
    float biasO[4][4];   // bias2[d] for d = 16*dt + 4*q + r (d-major accO init)
    #pragma unroll
    for (int dt = 0; dt < 4; ++dt)
        #pragma unroll
        for (int r = 0; r < 4; ++r) biasO[dt][r] = bias2[16 * dt + 4 * q + r];

    // prefetch first tile into registers
    float4 pf[4];
    #pragma unroll
    for (int i = 0; i < 4; ++i)
        pf[i] = *(const float4*)(xg + (size_t)(16 * i) * NN + g * 64);

    int p = 0;
    for (int t = g; t < NN / 64; t += G3) {
        const int n0 = t * 64;
        // ---- commit prefetched tile to LDS as bf16
        u16* xp = xsb[p];
        #pragma unroll
        for (int i = 0; i < 4; ++i) {
            int c = 16 * i + sc;
            uint2 pk;
            pk.x = pack2(pf[i].x, pf[i].y);
            pk.y = pack2(pf[i].z, pf[i].w);
            *(uint2*)&xp[c * SXB + sn] = pk;
        }
        __syncthreads();   // single barrier per tile
        if (t + G3 < NN / 64) {
            #pragma unroll
            for (int i = 0; i < 4; ++i)
                pf[i] = *(const float4*)(xg + (size_t)(16 * i) * NN + (t + G3) * 64);
        }
        // ---- GEMM A: accQ = q (n-major, for stats); accO = o = x@wvln^T + bias2 (d-major)
        f32x4_t accQ[4], accO[4];
        #pragma unroll
        for (int t4 = 0; t4 < 4; ++t4)
            accQ[t4] = (f32x4_t){biasQ[t4], biasQ[t4], biasQ[t4], biasQ[t4]};
        #pragma unroll
        for (int dt = 0; dt < 4; ++dt)
            accO[dt] = (f32x4_t){biasO[dt][0], biasO[dt][1], biasO[dt][2], biasO[dt][3]};
        #pragma unroll
        for (int ks = 0; ks < 2; ++ks) {
            union { u16 u[8]; bf16x8_t v; } af;   // x^T[n][c] frag, bf16 direct
            #pragma unroll
            for (int j = 0; j < 8; ++j)
                af.u[j] = xp[(ks * 32 + q * 8 + j) * SXB + 16 * w + l15];
            #pragma unroll
            for (int t4 = 0; t4 < 4; ++t4) {
                bf16x8_t bq = *(const bf16x8_t*)(w_q_bf + (16 * t4 + l15) * 64 + ks * 32 + q * 8);
                accQ[t4] = __builtin_amdgcn_mfma_f32_16x16x32_bf16(af.v, bq, accQ[t4], 0, 0, 0);
            }
            #pragma unroll
            for (int dt = 0; dt < 4; ++dt) {
                bf16x8_t aw = *(const bf16x8_t*)(wvln_bf + (16 * dt + l15) * 64 + ks * 32 + q * 8);
                accO[dt] = __builtin_amdgcn_mfma_f32_16x16x32_bf16(aw, af.v, accO[dt], 0, 0, 0);
            }
        }
        // ---- q stats via DPP: mu, q2s; q2; w_row = 1/max(||q2||, 1e-12*(q2s+eps))
        float mu[4], q2s[4];
        #pragma unroll
        for (int r = 0; r < 4; ++r) {
            float a0 = accQ[0][r], a1 = accQ[1][r], a2 = accQ[2][r], a3 = accQ[3][r];
            float s1 = row_red16(a0 + a1 + a2 + a3);
            float s2 = row_red16(a0 * a0 + a1 * a1 + a2 * a2 + a3 * a3);
            mu[r] = s1 * 0.015625f;
            q2s[r] = s2 - 64.f * mu[r] * mu[r];
        }
        float q2v[4][4];
        float s4[4] = {0.f, 0.f, 0.f, 0.f};
        #pragma unroll
        for (int t4 = 0; t4 < 4; ++t4)
            #pragma unroll
            for (int r = 0; r < 4; ++r) {
                float d = accQ[t4][r] - mu[r];
                float v2 = d * d;
                q2v[t4][r] = v2;
                s4[r] += v2 * v2;
            }
        float w_row[4];
        #pragma unroll
        for (int r = 0; r < 4; ++r) {
            float s = row_red16(s4[r]);
            w_row[r] = 1.f / fmaxf(sqrtf(s), 1e-12f * (q2s[r] + 1e-7f));
        }
        // ---- redistribute w_row: row n=16w+4q+r -> lane col l15 (same wave only)
        if (l15 == 0) {
            #pragma unroll
            for (int r = 0; r < 4; ++r) wrow_s[w][4 * q + r] = w_row[r];
        }
        // ---- q2 -> qt LDS ([n][c] bf16, same-wave rows)
        #pragma unroll
        for (int t4 = 0; t4 < 4; ++t4)
            #pragma unroll
            for (int r = 0; r < 4; ++r)
                qt[(16 * w + 4 * q + r) * STK + 16 * t4 + l15] = f2bf(q2v[t4][r]);
        // ---- GEMM B (d-major): t2[d][n] = sum_c kvw[d][c]-frag * q2[n][c]
        f32x4_t accB[4];
        #pragma unroll
        for (int dt = 0; dt < 4; ++dt) accB[dt] = (f32x4_t){0.f, 0.f, 0.f, 0.f};
        #pragma unroll
        for (int ks = 0; ks < 2; ++ks) {
            union { bf16x8_t v; uint2 h[2]; } b2;   // q2[n][c] frag as B-operand
            const u16* bp = &qt[(16 * w + l15) * STK + ks * 32 + q * 8];
            b2.h[0] = *(const uint2*)bp;
            b2.h[1] = *(const uint2*)(bp + 4);
            #pragma unroll
            for (int dt = 0; dt < 4; ++dt) {
                bf16x8_t ak = *(const bf16x8_t*)(kvb + (16 * dt + l15) * 64 + ks * 32 + q * 8);
                accB[dt] = __builtin_amdgcn_mfma_f32_16x16x32_bf16(ak, b2.v, accB[dt], 0, 0, 0);
            }
        }
        float wr = wrow_s[w][l15];
        // ---- epilogue: out[d][n] = o + w_row[n]*t2, direct register stores
        #pragma unroll
        for (int dt = 0; dt < 4; ++dt) {
            float* op = out + ((size_t)(b * 64 + 16 * dt + 4 * q)) * NN + n0 + 16 * w + l15;
            #pragma unroll
            for (int r = 0; r < 4; ++r)
                op[(size_t)r * NN] = accO[dt][r] + wr * accB[dt][r];
        }
        p ^= 1;
    }
}

extern "C" void kernel_launch(void* const* d_in, const int* in_sizes, int n_in,
                              void* d_out, int out_size, void* d_ws, size_t ws_size,
                              hipStream_t stream) {
    const float* x     = (const float*)d_in[0];
    const float* w_qkv = (const float*)d_in[1];
    const float* b_qkv = (const float*)d_in[2];
    const float* w_ln  = (const float*)d_in[3];
    const float* b_ln  = (const float*)d_in[4];
    float* out = (float*)d_out;
    char* ws = (char*)d_ws;
    // byte layout (total 12.88 MB, unchanged)
    float* kvu_part = (float*)(ws);                       // 8*96*4096 f32
    float* ksq_part = (float*)(ws + 12582912);            // 8*96*64 f32
    u16*   kvw_t    = (u16*)  (ws + 12779520);            // 8*4096 bf16
    u16*   w_kv_bf  = (u16*)  (ws + 12845056);            // 128*64 bf16
    u16*   w_q_bf   = (u16*)  (ws + 12861440);            // 64*64 bf16
    u16*   wvln_bf  = (u16*)  (ws + 12869632);            // 64*64 bf16
    float* bias2    = (float*)(ws + 12877824);            // 64 f32

    k0_prep<<<dim3(65), dim3(256), 0, stream>>>(w_qkv, b_qkv, w_ln, b_ln,
                                                w_kv_bf, w_q_bf, wvln_bf, bias2);
    k1_kv<<<dim3(G1, 8), dim3(256), 0, stream>>>(x, w_kv_bf, b_qkv, kvu_part, ksq_part);
    k2_kvw<<<dim3(16, 8), dim3(256), 0, stream>>>(kvu_part, ksq_part, w_ln, kvw_t);
    k3_out<<<dim3(G3, 8), dim3(256), 0, stream>>>(x, w_q_bf, wvln_bf, b_qkv, bias2, kvw_t, out);
}